// Round 6
// baseline (1473.845 us; speedup 1.0000x reference)
//
#include <hip/hip_runtime.h>
#include <math.h>

// Sizes fixed by setup_inputs(): A=1024, C=128, CP=128, H=8, kph=16
constexpr float EPSF = 1e-6f;

typedef __attribute__((ext_vector_type(8))) short short8;
typedef __attribute__((ext_vector_type(4))) float f32x4;

static __device__ __forceinline__ short f2bf(float f) {
    unsigned u = __builtin_bit_cast(unsigned, f);
    u += 0x7FFF + ((u >> 16) & 1);   // round-to-nearest-even
    return (short)(u >> 16);
}

// ---------------------------------------------------------------------------
// K1 (MFMA): fused pass over pair_act [1024][1024][128] f32.
// Per (i,j): LN(f2n) -> bf16 -> MFMA vs B=[w_pm | w2d | pad] (144 cols)
//   -> cols 0..127: +b_pm -> LN(mn) -> masked u/vmix accumulation
//   -> cols 128..135: pair_bias (no LN)
// Block = 256 thr (4 waves), tile = 64 i x 64 j; wave m owns rows m*16..+15.
// Zero barriers in the i-loop. LDS: As 16K + (Bt 36K aliased-> u_sh 32K)
// = 52 KB -> 2 blocks/CU (8 waves/CU).
// ---------------------------------------------------------------------------
__global__ __launch_bounds__(256, 2)
void k1_pair(const float* __restrict__ pair_act, const float* __restrict__ pair_mask,
             const float* __restrict__ f2n_s, const float* __restrict__ f2n_b,
             const float* __restrict__ mn_s, const float* __restrict__ mn_b,
             const float* __restrict__ w2d, const float* __restrict__ w_pm,
             const float* __restrict__ b_pm,
             float* __restrict__ pbias,   // [i][h][j]  (i*8+h)*1024+j
             float* __restrict__ u_part,  // [jt=16][i][d]
             float* __restrict__ v_part)  // [it=16][j][d]
{
    __shared__ __align__(16) char As[64 * 256];    // 16 KB bf16 A-tile, swizzled
    __shared__ __align__(16) char BtU[144 * 256];  // 36 KB: Bt staging, then u_sh

    const int tid = threadIdx.x;
    const int m = tid >> 6;            // wave id (row-tile)
    const int lane = tid & 63;
    const int cpart = lane & 15;       // 16-lane sub-group index
    const int q = lane >> 4;           // quad index 0..3
    const int it = blockIdx.x >> 4, jt = blockIdx.x & 15;
    const int i0 = it << 6;
    const int j0 = jt << 6;

    // ---- stage B^T (w_pm cols 0..127, w2d cols 128..135, zero pad) ----
    for (int idx = tid; idx < 144 * 128; idx += 256) {
        int col = idx >> 7, k = idx & 127;
        float w;
        if (col < 128)       w = w_pm[k * 128 + col];
        else if (col < 136)  w = w2d[k * 8 + (col - 128)];
        else                 w = 0.f;
        int byte = col * 256 + ((2 * k) ^ ((col & 7) << 4));
        *(short*)(BtU + byte) = f2bf(w);
    }
    __syncthreads();

    // ---- hoist B fragments to registers: 9 col-tiles x 4 k-steps ----
    short8 bfr[9][4];
#pragma unroll
    for (int n = 0; n < 9; n++) {
#pragma unroll
        for (int kk = 0; kk < 4; kk++) {
            int col = n * 16 + cpart;
            int off = (kk * 64 + q * 16) ^ ((col & 7) << 4);
            bfr[n][kk] = *(const short8*)(BtU + col * 256 + off);
        }
    }
    __syncthreads();

    // ---- Bt is dead; reuse as u accumulator [64 i][128 d] (32 KB) ----
    float* u_sh = (float*)BtU;
#pragma unroll
    for (int k = 0; k < 8; k++)
        ((f32x4*)u_sh)[tid + (k << 8)] = (f32x4){0.f, 0.f, 0.f, 0.f};
    __syncthreads();

    // ---- per-lane parameter registers ----
    float f2s[8], f2b[8];
#pragma unroll
    for (int v = 0; v < 8; v++) {
        f2s[v] = f2n_s[cpart * 8 + v];
        f2b[v] = f2n_b[cpart * 8 + v];
    }
    float mns[8], mnb[8], bp[8];
#pragma unroll
    for (int n = 0; n < 8; n++) {
        mns[n] = mn_s[n * 16 + cpart];
        mnb[n] = mn_b[n * 16 + cpart];
        bp[n]  = b_pm[n * 16 + cpart];
    }

    float vx[8][4];   // vmix accumulators: [n][jj] for this lane's cols/rows
#pragma unroll
    for (int n = 0; n < 8; n++)
#pragma unroll
        for (int jj = 0; jj < 4; jj++) vx[n][jj] = 0.f;

    const int arow = m * 16 + cpart;        // A-frag LDS row for MFMA reads
    const int jrow0 = j0 + m * 16 + q * 4;  // this lane's first output row (j)

    // ---- prologue: load rows + mask of i = i0 ----
    float4 ldA[4][2], ldB[4][2];
    float4 mkA, mkB;
#pragma unroll
    for (int t = 0; t < 4; t++) {
        int row_l = m * 16 + t * 4 + q;
        const float4* src = (const float4*)(pair_act +
            ((size_t)i0 * 1024 + (size_t)(j0 + row_l)) * 128 + cpart * 8);
        ldA[t][0] = src[0];
        ldA[t][1] = src[1];
    }
    mkA = *(const float4*)&pair_mask[(size_t)i0 * 1024 + jrow0];

    for (int ii = 0; ii < 64; ii++) {
        const int i_abs = i0 + ii;

        // (1) issue next-row loads (one-deep pipeline)
        if (ii < 63) {
#pragma unroll
            for (int t = 0; t < 4; t++) {
                int row_l = m * 16 + t * 4 + q;
                const float4* src = (const float4*)(pair_act +
                    ((size_t)(i_abs + 1) * 1024 + (size_t)(j0 + row_l)) * 128 + cpart * 8);
                ldB[t][0] = src[0];
                ldB[t][1] = src[1];
            }
            mkB = *(const float4*)&pair_mask[(size_t)(i_abs + 1) * 1024 + jrow0];
        }
        const float mkv[4] = {mkA.x, mkA.y, mkA.z, mkA.w};

        // (2) LN1 on ldA + bf16 + stage to LDS (own rows only; no barrier)
#pragma unroll
        for (int t = 0; t < 4; t++) {
            int row_l = m * 16 + t * 4 + q;
            float xv[8];
            xv[0] = ldA[t][0].x; xv[1] = ldA[t][0].y; xv[2] = ldA[t][0].z; xv[3] = ldA[t][0].w;
            xv[4] = ldA[t][1].x; xv[5] = ldA[t][1].y; xv[6] = ldA[t][1].z; xv[7] = ldA[t][1].w;
            float s = 0.f, ss = 0.f;
#pragma unroll
            for (int v = 0; v < 8; v++) { s += xv[v]; ss += xv[v] * xv[v]; }
#pragma unroll
            for (int off = 1; off < 16; off <<= 1) {
                s += __shfl_xor(s, off);
                ss += __shfl_xor(ss, off);
            }
            float mean = s * 0.0078125f;
            float rinv = rsqrtf(fmaxf(ss * 0.0078125f - mean * mean, 0.f) + EPSF);
            short hs[8];
#pragma unroll
            for (int v = 0; v < 8; v++)
                hs[v] = f2bf((xv[v] - mean) * rinv * f2s[v] + f2b[v]);
            short8 pk = (short8){hs[0], hs[1], hs[2], hs[3], hs[4], hs[5], hs[6], hs[7]};
            *(short8*)(As + row_l * 256 + ((cpart * 16) ^ ((row_l & 7) << 4))) = pk;
        }

        // (3) MFMA: A-frags (own rows) x hoisted B-frags
        short8 af[4];
#pragma unroll
        for (int kk = 0; kk < 4; kk++)
            af[kk] = *(const short8*)(As + arow * 256 +
                                      ((kk * 64 + q * 16) ^ ((arow & 7) << 4)));
        f32x4 acc[9];
#pragma unroll
        for (int n = 0; n < 9; n++) acc[n] = (f32x4){0.f, 0.f, 0.f, 0.f};
#pragma unroll
        for (int n = 0; n < 9; n++)
#pragma unroll
            for (int kk = 0; kk < 4; kk++)
                acc[n] = __builtin_amdgcn_mfma_f32_16x16x32_bf16(af[kk], bfr[n][kk], acc[n], 0, 0, 0);

        // (4) LN2 over cols 0..127 (per output row jj), u/vmix accumulation
        float mean2[4], rinv2[4];
#pragma unroll
        for (int jj = 0; jj < 4; jj++) {
            float s = 0.f, ss = 0.f;
#pragma unroll
            for (int n = 0; n < 8; n++) {
                float tv = acc[n][jj] + bp[n];
                s += tv; ss += tv * tv;
            }
#pragma unroll
            for (int off = 1; off < 16; off <<= 1) {
                s += __shfl_xor(s, off);
                ss += __shfl_xor(ss, off);
            }
            mean2[jj] = s * 0.0078125f;
            rinv2[jj] = rsqrtf(fmaxf(ss * 0.0078125f - mean2[jj] * mean2[jj], 0.f) + EPSF);
        }
        float up[8];
#pragma unroll
        for (int n = 0; n < 8; n++) {
            float u_acc = 0.f;
#pragma unroll
            for (int jj = 0; jj < 4; jj++) {
                float pm = (acc[n][jj] + bp[n] - mean2[jj]) * rinv2[jj] * mns[n] + mnb[n];
                float w = pm * mkv[jj];
                u_acc += w;
                vx[n][jj] += w;
            }
            up[n] = u_acc;
        }
        // reduce u across the 4 q-groups, then single atomic per (n, cpart)
#pragma unroll
        for (int n = 0; n < 8; n++) {
            up[n] += __shfl_xor(up[n], 16);
            up[n] += __shfl_xor(up[n], 32);
        }
        if (q == 0) {
#pragma unroll
            for (int n = 0; n < 8; n++)
                atomicAdd(&u_sh[(ii << 7) + n * 16 + cpart], up[n]);
        }

        // (5) pair bias: col-tile n=8 holds p @ w2d (cols 128..135)
        if (cpart < 8) {
            *(float4*)&pbias[(((size_t)i_abs * 8 + cpart) << 10) + jrow0] =
                *(float4*)&acc[8];
        }

        // (6) rotate row registers
#pragma unroll
        for (int t = 0; t < 4; t++) { ldA[t][0] = ldB[t][0]; ldA[t][1] = ldB[t][1]; }
        mkA = mkB;
    }

    // ---- vmix partials: unique writer per (it, j, d) ----
#pragma unroll
    for (int n = 0; n < 8; n++)
#pragma unroll
        for (int jj = 0; jj < 4; jj++)
            v_part[((size_t)it * 1024 + jrow0 + jj) * 128 + n * 16 + cpart] = vx[n][jj];

    __syncthreads();
    // ---- u partials: unique writer per (jt, i, d) ----
    float* ub = &u_part[((size_t)jt * 1024 + i0) * 128];
    for (int idx = tid; idx < 2048; idx += 256)
        ((float4*)ub)[idx] = ((float4*)u_sh)[idx];
}

// ---------------------------------------------------------------------------
// Mask row sums: msr[i] = sum_j pair_mask[i][j]
// ---------------------------------------------------------------------------
__global__ __launch_bounds__(256)
void k_rowsum(const float* __restrict__ pm, float* __restrict__ msr) {
    int i = (blockIdx.x << 2) + (threadIdx.x >> 6);
    int lane = threadIdx.x & 63;
    const float4* row = (const float4*)&pm[(size_t)i << 10];
    float s = 0.f;
#pragma unroll
    for (int q = 0; q < 4; q++) {
        float4 v = row[(q << 6) + lane];
        s += v.x + v.y + v.z + v.w;
    }
#pragma unroll
    for (int off = 32; off; off >>= 1) s += __shfl_xor(s, off);
    if (lane == 0) msr[i] = s;
}

// ---------------------------------------------------------------------------
// Mask col sums: msc[j] = sum_i pair_mask[i][j]; grid 32, block 512
// ---------------------------------------------------------------------------
__global__ __launch_bounds__(512)
void k_colsum(const float* __restrict__ pm, float* __restrict__ msc) {
    __shared__ float red[512];
    int jb = blockIdx.x << 5;
    int jtl = threadIdx.x & 31, ig = threadIdx.x >> 5;  // 16 i-groups
    float s = 0.f;
    for (int i = ig; i < 1024; i += 16) s += pm[((size_t)i << 10) + jb + jtl];
    red[threadIdx.x] = s;
    __syncthreads();
    for (int st = 8; st > 0; st >>= 1) {
        if (ig < st) red[threadIdx.x] += red[threadIdx.x + (st << 5)];
        __syncthreads();
    }
    if (ig == 0) msc[jb + jtl] = red[jtl];
}

// ---------------------------------------------------------------------------
// Finalize u and vmix: sum 16 partial slices, divide by (mask sum + EPS)
// grid 1024 x 256: blocks [0,512) -> u, [512,1024) -> vmix
// ---------------------------------------------------------------------------
__global__ __launch_bounds__(256)
void k_fin(const float* __restrict__ up, const float* __restrict__ vp,
           const float* __restrict__ msr, const float* __restrict__ msc,
           float* __restrict__ uf, float* __restrict__ vf) {
    int b = blockIdx.x;
    if (b < 512) {
        int idx = (b << 8) + threadIdx.x;
        float s = 0.f;
#pragma unroll
        for (int t = 0; t < 16; t++) s += up[((size_t)t << 17) + idx];
        uf[idx] = s / (msr[idx >> 7] + EPSF);
    } else {
        int idx = ((b - 512) << 8) + threadIdx.x;
        float s = 0.f;
#pragma unroll
        for (int t = 0; t < 16; t++) s += vp[((size_t)t << 17) + idx];
        vf[idx] = s / (msc[idx >> 7] + EPSF);
    }
}

// ---------------------------------------------------------------------------
// K3: x = LN(atom_act); qa = x*(1+u); ka = x*(1+vmix). One wave per row.
// ---------------------------------------------------------------------------
__global__ __launch_bounds__(256)
void k3_act(const float* __restrict__ aa, const float* __restrict__ qns,
            const float* __restrict__ qnb, const float* __restrict__ uf,
            const float* __restrict__ vf, float* __restrict__ qa,
            float* __restrict__ ka) {
    int i = (blockIdx.x << 2) + (threadIdx.x >> 6);
    int lane = threadIdx.x & 63, c0 = lane << 1;
    float2 x2 = *(const float2*)&aa[(i << 7) + c0];
    float s = x2.x + x2.y, ss = x2.x * x2.x + x2.y * x2.y;
#pragma unroll
    for (int off = 32; off; off >>= 1) {
        s += __shfl_xor(s, off);
        ss += __shfl_xor(ss, off);
    }
    float m = s * 0.0078125f;
    float rinv = rsqrtf(fmaxf(ss * 0.0078125f - m * m, 0.f) + EPSF);
    float xa = (x2.x - m) * rinv * qns[c0] + qnb[c0];
    float xb = (x2.y - m) * rinv * qns[c0 + 1] + qnb[c0 + 1];
    float2 u2 = *(const float2*)&uf[(i << 7) + c0];
    float2 v2 = *(const float2*)&vf[(i << 7) + c0];
    *(float2*)&qa[(i << 7) + c0] = make_float2(xa * (1.f + u2.x), xb * (1.f + u2.y));
    *(float2*)&ka[(i << 7) + c0] = make_float2(xa * (1.f + v2.x), xb * (1.f + v2.y));
}

// ---------------------------------------------------------------------------
// K4: q/k/v/gate projections. grid (64 rowblocks, 4 mats), block 256.
// ---------------------------------------------------------------------------
__global__ __launch_bounds__(256)
void k4_proj(const float* __restrict__ qa, const float* __restrict__ ka,
             const float* __restrict__ wq, const float* __restrict__ wk,
             const float* __restrict__ wv, const float* __restrict__ wg,
             const float* __restrict__ bg, float* __restrict__ qh,
             float* __restrict__ kh, float* __restrict__ vT,
             float* __restrict__ gate) {
    __shared__ float Wl[128 * 128];
    __shared__ float inl[16 * 128];
    int m = blockIdx.y, rb = blockIdx.x, t = threadIdx.x;
    const float* W = (m == 0) ? wq : (m == 1) ? wk : (m == 2) ? wv : wg;
    const float* in = (m == 0 || m == 3) ? qa : ka;
#pragma unroll
    for (int k = 0; k < 16; k++)
        ((float4*)Wl)[(k << 8) + t] = ((const float4*)W)[(k << 8) + t];
#pragma unroll
    for (int k = 0; k < 2; k++)
        ((float4*)inl)[(k << 8) + t] = ((const float4*)&in[rb << 11])[(k << 8) + t];
    __syncthreads();

    int c = t & 127, r2 = t >> 7;
    float acc[8] = {0.f, 0.f, 0.f, 0.f, 0.f, 0.f, 0.f, 0.f};
    const float* wcol = &Wl[c];
    const float* ib = &inl[(r2 << 3) * 128];
#pragma unroll 8
    for (int k = 0; k < 128; k++) {
        float wvv = wcol[k << 7];
#pragma unroll
        for (int r = 0; r < 8; r++) acc[r] += ib[(r << 7) + k] * wvv;
    }
    int h = c >> 4, kk = c & 15;
    int row0 = (rb << 4) + (r2 << 3);
    if (m == 0) {
#pragma unroll
        for (int r = 0; r < 8; r++) qh[(h << 14) + ((row0 + r) << 4) + kk] = acc[r] * 0.25f;
    } else if (m == 1) {
#pragma unroll
        for (int r = 0; r < 8; r++) kh[(h << 14) + ((row0 + r) << 4) + kk] = acc[r];
    } else if (m == 2) {
#pragma unroll
        for (int r = 0; r < 8; r++) vT[(h << 14) + (kk << 10) + row0 + r] = acc[r];
    } else {
        float b = bg[c];
#pragma unroll
        for (int r = 0; r < 8; r++)
            gate[((row0 + r) << 7) + c] = 1.f / (1.f + __expf(-(acc[r] + b)));
    }
}

// ---------------------------------------------------------------------------
// K5: attention. One wave per (h,i). logits in regs, softmax via shfl.
// ---------------------------------------------------------------------------
__global__ __launch_bounds__(64)
void k5_attn(const float* __restrict__ qh, const float* __restrict__ kh,
             const float* __restrict__ vT, const float* __restrict__ pbias,
             const float* __restrict__ gate, float* __restrict__ wag) {
    __shared__ float p_lds[1024];
    int b = blockIdx.x;
    int h = b >> 10, i = b & 1023;
    int lane = threadIdx.x;

    const float* qp = &qh[(h << 14) + (i << 4)];
    float ql[16];
#pragma unroll
    for (int kk = 0; kk < 16; kk++) ql[kk] = qp[kk];

    const float* kbase = &kh[h << 14];
    const float* bias = &pbias[(((size_t)i << 3) + h) << 10];

    float lg[16];
    float mx = -1e30f;
#pragma unroll
    for (int jc = 0; jc < 16; jc++) {
        int j = (jc << 6) + lane;
        const float4* kr = (const float4*)&kbase[j << 4];
        float4 ka = kr[0], kb = kr[1], kc = kr[2], kd = kr[3];
        float acc = bias[j];
        acc += ql[0] * ka.x + ql[1] * ka.y + ql[2] * ka.z + ql[3] * ka.w;
        acc += ql[4] * kb.x + ql[5] * kb.y + ql[6] * kb.z + ql[7] * kb.w;
        acc += ql[8] * kc.x + ql[9] * kc.y + ql[10] * kc.z + ql[11] * kc.w;
        acc += ql[12] * kd.x + ql[13] * kd.y + ql[14] * kd.z + ql[15] * kd.w;
        lg[jc] = acc;
        mx = fmaxf(mx, acc);
    }
#pragma unroll
    for (int off = 32; off; off >>= 1) mx = fmaxf(mx, __shfl_xor(mx, off));
    float S = 0.f;
#pragma unroll
    for (int jc = 0; jc < 16; jc++) {
        float p = __expf(lg[jc] - mx);
        S += p;
        p_lds[(jc << 6) + lane] = p;
    }
#pragma unroll
    for (int off = 32; off; off >>= 1) S += __shfl_xor(S, off);
    float inv = 1.f / S;
    __syncthreads();

    int jj = lane >> 4, kk = lane & 15;
    const float* vp = &vT[(h << 14) + (kk << 10)];
    float acc = 0.f;
#pragma unroll 4
    for (int jb = 0; jb < 64; jb++) {
        int j4 = (jb << 4) + (jj << 2);
        float4 p4 = *(const float4*)&p_lds[j4];
        float4 v4 = *(const float4*)&vp[j4];
        acc += p4.x * v4.x + p4.y * v4.y + p4.z * v4.z + p4.w * v4.w;
    }
    acc += __shfl_xor(acc, 16);
    acc += __shfl_xor(acc, 32);
    if (lane < 16) {
        float g = gate[(i << 7) + (h << 4) + kk];
        wag[(i << 7) + (h << 4) + kk] = acc * inv * g;
    }
}

// ---------------------------------------------------------------------------
// K6: out = wag @ wo + bo
// ---------------------------------------------------------------------------
__global__ __launch_bounds__(256)
void k6_out(const float* __restrict__ wag, const float* __restrict__ wo,
            const float* __restrict__ bo, float* __restrict__ out) {
    __shared__ float Wl[128 * 128];
    __shared__ float inl[16 * 128];
    int rb = blockIdx.x, t = threadIdx.x;
#pragma unroll
    for (int k = 0; k < 16; k++)
        ((float4*)Wl)[(k << 8) + t] = ((const float4*)wo)[(k << 8) + t];
#pragma unroll
    for (int k = 0; k < 2; k++)
        ((float4*)inl)[(k << 8) + t] = ((const float4*)&wag[rb << 11])[(k << 8) + t];
    __syncthreads();

    int c = t & 127, r2 = t >> 7;
    float acc[8] = {0.f, 0.f, 0.f, 0.f, 0.f, 0.f, 0.f, 0.f};
    const float* wcol = &Wl[c];
    const float* ib = &inl[(r2 << 3) * 128];
#pragma unroll 8
    for (int k = 0; k < 128; k++) {
        float wvv = wcol[k << 7];
#pragma unroll
        for (int r = 0; r < 8; r++) acc[r] += ib[(r << 7) + k] * wvv;
    }
    int row0 = (rb << 4) + (r2 << 3);
    float b = bo[c];
#pragma unroll
    for (int r = 0; r < 8; r++) out[((row0 + r) << 7) + c] = acc[r] + b;
}

// ---------------------------------------------------------------------------
extern "C" void kernel_launch(void* const* d_in, const int* in_sizes, int n_in,
                              void* d_out, int out_size, void* d_ws, size_t ws_size,
                              hipStream_t stream) {
    const float* atom_act  = (const float*)d_in[0];
    const float* pair_act  = (const float*)d_in[1];
    // d_in[2] atom_mask: unused by reference output
    const float* pair_mask = (const float*)d_in[3];
    const float* qn_s = (const float*)d_in[4];
    const float* qn_b = (const float*)d_in[5];
    const float* f2n_s = (const float*)d_in[6];
    const float* f2n_b = (const float*)d_in[7];
    const float* mn_s = (const float*)d_in[8];
    const float* mn_b = (const float*)d_in[9];
    const float* w2d  = (const float*)d_in[10];
    const float* w_pm = (const float*)d_in[11];
    const float* b_pm = (const float*)d_in[12];
    const float* wq = (const float*)d_in[13];
    const float* wk = (const float*)d_in[14];
    const float* wv = (const float*)d_in[15];
    const float* wg = (const float*)d_in[16];
    const float* bg = (const float*)d_in[17];
    const float* wo = (const float*)d_in[18];
    const float* bo = (const float*)d_in[19];

    float* ws = (float*)d_ws;
    float* pbias  = ws;                          // 8M floats  (32 MB)
    float* u_part = pbias + 8 * 1024 * 1024;     // 16*1024*128 (8 MB)
    float* v_part = u_part + 16 * 1024 * 128;    // 16*1024*128 (8 MB)
    float* msr    = v_part + 16 * 1024 * 128;    // 1024
    float* msc    = msr + 1024;                  // 1024
    float* uf     = msc + 1024;                  // 131072
    float* vf     = uf + 131072;
    float* qa     = vf + 131072;
    float* ka     = qa + 131072;
    float* qh     = ka + 131072;
    float* kh     = qh + 131072;
    float* vT     = kh + 131072;
    float* gate   = vT + 131072;
    float* wag    = gate + 131072;
    (void)in_sizes; (void)n_in; (void)out_size; (void)ws_size;

    k_rowsum<<<256, 256, 0, stream>>>(pair_mask, msr);
    k_colsum<<<32, 512, 0, stream>>>(pair_mask, msc);
    k1_pair<<<256, 256, 0, stream>>>(pair_act, pair_mask, f2n_s, f2n_b, mn_s, mn_b,
                                     w2d, w_pm, b_pm, pbias, u_part, v_part);
    k_fin<<<1024, 256, 0, stream>>>(u_part, v_part, msr, msc, uf, vf);
    k3_act<<<256, 256, 0, stream>>>(atom_act, qn_s, qn_b, uf, vf, qa, ka);
    k4_proj<<<dim3(64, 4), 256, 0, stream>>>(qa, ka, wq, wk, wv, wg, bg, qh, kh, vT, gate);
    k5_attn<<<8192, 64, 0, stream>>>(qh, kh, vT, pbias, gate, wag);
    k6_out<<<64, 256, 0, stream>>>(wag, wo, bo, (float*)d_out);
}

// Round 8
// 975.077 us; speedup vs baseline: 1.5115x; 1.5115x over previous
//
#include <hip/hip_runtime.h>
#include <math.h>

// Sizes fixed by setup_inputs(): A=1024, C=128, CP=128, H=8, kph=16
constexpr float EPSF = 1e-6f;

typedef __attribute__((ext_vector_type(8))) short short8;
typedef __attribute__((ext_vector_type(4))) float f32x4;

static __device__ __forceinline__ short f2bf(float f) {
    unsigned u = __builtin_bit_cast(unsigned, f);
    u += 0x7FFF + ((u >> 16) & 1);   // round-to-nearest-even
    return (short)(u >> 16);
}

// ---------------------------------------------------------------------------
// K1 (MFMA): fused pass over pair_act [1024][1024][128] f32.
// Per (i,j): LN(f2n) -> bf16 -> MFMA vs B=[w_pm | w2d | pad] (144 cols)
//   -> cols 0..127: +b_pm -> LN(mn) -> masked u/vmix accumulation
//   -> cols 128..135: pair_bias (no LN)
// Block = 256 thr (4 waves); tile = 32 i x 64 j; wave m owns j-rows m*16..+15.
// Grid = 512 (32 it x 16 jt) -> 2 blocks/CU. Zero barriers in the i-loop.
// LDS: As 16K + (Bt 36K aliased-> u_sh 16K) = 52 KB.
// launch_bounds (256,1): R2 precedent compiles to ~196 VGPR (no spill), which
// still permits 2 waves/SIMD at runtime. (256,2) forced 128 VGPR + spill (R6).
// ---------------------------------------------------------------------------
__global__ __launch_bounds__(256, 1)
void k1_pair(const float* __restrict__ pair_act, const float* __restrict__ pair_mask,
             const float* __restrict__ f2n_s, const float* __restrict__ f2n_b,
             const float* __restrict__ mn_s, const float* __restrict__ mn_b,
             const float* __restrict__ w2d, const float* __restrict__ w_pm,
             const float* __restrict__ b_pm,
             float* __restrict__ pbias,   // [i][h][j]  (i*8+h)*1024+j
             float* __restrict__ u_part,  // [jt=16][i][d]
             float* __restrict__ v_part)  // [it=32][j][d]
{
    __shared__ __align__(16) char As[64 * 256];    // 16 KB bf16 A-tile, swizzled
    __shared__ __align__(16) char BtU[144 * 256];  // 36 KB: Bt staging, then u_sh

    const int tid = threadIdx.x;
    const int m = tid >> 6;            // wave id (row-tile)
    const int lane = tid & 63;
    const int cpart = lane & 15;       // 16-lane sub-group index
    const int q = lane >> 4;           // quad index 0..3
    const int it = blockIdx.x >> 4, jt = blockIdx.x & 15;
    const int i0 = it << 5;            // i-tile of 32
    const int j0 = jt << 6;

    // ---- stage B^T (w_pm cols 0..127, w2d cols 128..135, zero pad) ----
    for (int idx = tid; idx < 144 * 128; idx += 256) {
        int col = idx >> 7, k = idx & 127;
        float w;
        if (col < 128)       w = w_pm[k * 128 + col];
        else if (col < 136)  w = w2d[k * 8 + (col - 128)];
        else                 w = 0.f;
        int byte = col * 256 + ((2 * k) ^ ((col & 7) << 4));
        *(short*)(BtU + byte) = f2bf(w);
    }
    __syncthreads();

    // ---- hoist B fragments to registers: 9 col-tiles x 4 k-steps ----
    short8 bfr[9][4];
#pragma unroll
    for (int n = 0; n < 9; n++) {
#pragma unroll
        for (int kk = 0; kk < 4; kk++) {
            int col = n * 16 + cpart;
            int off = (kk * 64 + q * 16) ^ ((col & 7) << 4);
            bfr[n][kk] = *(const short8*)(BtU + col * 256 + off);
        }
    }
    __syncthreads();

    // ---- Bt is dead; reuse as u accumulator [32 i][128 d] (16 KB) ----
    float* u_sh = (float*)BtU;
#pragma unroll
    for (int k = 0; k < 4; k++)
        ((f32x4*)u_sh)[tid + (k << 8)] = (f32x4){0.f, 0.f, 0.f, 0.f};
    __syncthreads();

    // ---- per-lane parameter registers ----
    float f2s[8], f2b[8];
#pragma unroll
    for (int v = 0; v < 8; v++) {
        f2s[v] = f2n_s[cpart * 8 + v];
        f2b[v] = f2n_b[cpart * 8 + v];
    }
    float mns[8], mnb[8], bp[8];
#pragma unroll
    for (int n = 0; n < 8; n++) {
        mns[n] = mn_s[n * 16 + cpart];
        mnb[n] = mn_b[n * 16 + cpart];
        bp[n]  = b_pm[n * 16 + cpart];
    }

    float vx[8][4];   // vmix accumulators: [n][jj] for this lane's cols/rows
#pragma unroll
    for (int n = 0; n < 8; n++)
#pragma unroll
        for (int jj = 0; jj < 4; jj++) vx[n][jj] = 0.f;

    const int arow = m * 16 + cpart;        // A-frag LDS row for MFMA reads
    const int jrow0 = j0 + m * 16 + q * 4;  // this lane's first output row (j)

    // ---- prologue: load rows + mask of i = i0 ----
    float4 ldA[4][2], ldB[4][2];
    float4 mkA, mkB;
#pragma unroll
    for (int t = 0; t < 4; t++) {
        int row_l = m * 16 + t * 4 + q;
        const float4* src = (const float4*)(pair_act +
            ((size_t)i0 * 1024 + (size_t)(j0 + row_l)) * 128 + cpart * 8);
        ldA[t][0] = src[0];
        ldA[t][1] = src[1];
    }
    mkA = *(const float4*)&pair_mask[(size_t)i0 * 1024 + jrow0];

    for (int ii = 0; ii < 32; ii++) {
        const int i_abs = i0 + ii;

        // (1) issue next-row loads (one-deep pipeline)
        if (ii < 31) {
#pragma unroll
            for (int t = 0; t < 4; t++) {
                int row_l = m * 16 + t * 4 + q;
                const float4* src = (const float4*)(pair_act +
                    ((size_t)(i_abs + 1) * 1024 + (size_t)(j0 + row_l)) * 128 + cpart * 8);
                ldB[t][0] = src[0];
                ldB[t][1] = src[1];
            }
            mkB = *(const float4*)&pair_mask[(size_t)(i_abs + 1) * 1024 + jrow0];
        }
        const float mkv[4] = {mkA.x, mkA.y, mkA.z, mkA.w};

        // (2) LN1 on ldA + bf16 + stage to LDS (own rows only; no barrier)
#pragma unroll
        for (int t = 0; t < 4; t++) {
            int row_l = m * 16 + t * 4 + q;
            float xv[8];
            xv[0] = ldA[t][0].x; xv[1] = ldA[t][0].y; xv[2] = ldA[t][0].z; xv[3] = ldA[t][0].w;
            xv[4] = ldA[t][1].x; xv[5] = ldA[t][1].y; xv[6] = ldA[t][1].z; xv[7] = ldA[t][1].w;
            float s = 0.f, ss = 0.f;
#pragma unroll
            for (int v = 0; v < 8; v++) { s += xv[v]; ss += xv[v] * xv[v]; }
#pragma unroll
            for (int off = 1; off < 16; off <<= 1) {
                s += __shfl_xor(s, off);
                ss += __shfl_xor(ss, off);
            }
            float mean = s * 0.0078125f;
            float rinv = rsqrtf(fmaxf(ss * 0.0078125f - mean * mean, 0.f) + EPSF);
            short hs[8];
#pragma unroll
            for (int v = 0; v < 8; v++)
                hs[v] = f2bf((xv[v] - mean) * rinv * f2s[v] + f2b[v]);
            short8 pk = (short8){hs[0], hs[1], hs[2], hs[3], hs[4], hs[5], hs[6], hs[7]};
            *(short8*)(As + row_l * 256 + ((cpart * 16) ^ ((row_l & 7) << 4))) = pk;
        }

        // (3) MFMA: A-frags (own rows) x hoisted B-frags
        short8 af[4];
#pragma unroll
        for (int kk = 0; kk < 4; kk++)
            af[kk] = *(const short8*)(As + arow * 256 +
                                      ((kk * 64 + q * 16) ^ ((arow & 7) << 4)));
        f32x4 acc[9];
#pragma unroll
        for (int n = 0; n < 9; n++) acc[n] = (f32x4){0.f, 0.f, 0.f, 0.f};
#pragma unroll
        for (int n = 0; n < 9; n++)
#pragma unroll
            for (int kk = 0; kk < 4; kk++)
                acc[n] = __builtin_amdgcn_mfma_f32_16x16x32_bf16(af[kk], bfr[n][kk], acc[n], 0, 0, 0);

        // (4) LN2 over cols 0..127 (per output row jj), u/vmix accumulation
        float mean2[4], rinv2[4];
#pragma unroll
        for (int jj = 0; jj < 4; jj++) {
            float s = 0.f, ss = 0.f;
#pragma unroll
            for (int n = 0; n < 8; n++) {
                float tv = acc[n][jj] + bp[n];
                s += tv; ss += tv * tv;
            }
#pragma unroll
            for (int off = 1; off < 16; off <<= 1) {
                s += __shfl_xor(s, off);
                ss += __shfl_xor(ss, off);
            }
            mean2[jj] = s * 0.0078125f;
            rinv2[jj] = rsqrtf(fmaxf(ss * 0.0078125f - mean2[jj] * mean2[jj], 0.f) + EPSF);
        }
        float up[8];
#pragma unroll
        for (int n = 0; n < 8; n++) {
            float u_acc = 0.f;
#pragma unroll
            for (int jj = 0; jj < 4; jj++) {
                float pm = (acc[n][jj] + bp[n] - mean2[jj]) * rinv2[jj] * mns[n] + mnb[n];
                float w = pm * mkv[jj];
                u_acc += w;
                vx[n][jj] += w;
            }
            up[n] = u_acc;
        }
        // reduce u across the 4 q-groups, then single atomic per (n, cpart)
#pragma unroll
        for (int n = 0; n < 8; n++) {
            up[n] += __shfl_xor(up[n], 16);
            up[n] += __shfl_xor(up[n], 32);
        }
        if (q == 0) {
#pragma unroll
            for (int n = 0; n < 8; n++)
                atomicAdd(&u_sh[(ii << 7) + n * 16 + cpart], up[n]);
        }

        // (5) pair bias: col-tile n=8 holds p @ w2d (cols 128..135)
        if (cpart < 8) {
            *(float4*)&pbias[(((size_t)i_abs * 8 + cpart) << 10) + jrow0] =
                *(float4*)&acc[8];
        }

        // (6) rotate row registers
#pragma unroll
        for (int t = 0; t < 4; t++) { ldA[t][0] = ldB[t][0]; ldA[t][1] = ldB[t][1]; }
        mkA = mkB;
    }

    // ---- vmix partials: unique writer per (it, j, d), it in [0,32) ----
#pragma unroll
    for (int n = 0; n < 8; n++)
#pragma unroll
        for (int jj = 0; jj < 4; jj++)
            v_part[((size_t)it * 1024 + jrow0 + jj) * 128 + n * 16 + cpart] = vx[n][jj];

    __syncthreads();
    // ---- u partials: unique writer per (jt, i0..i0+31, d) ----
    float* ub = &u_part[((size_t)jt * 1024 + i0) * 128];
    for (int idx = tid; idx < 1024; idx += 256)
        ((float4*)ub)[idx] = ((float4*)u_sh)[idx];
}

// ---------------------------------------------------------------------------
// Mask row sums: msr[i] = sum_j pair_mask[i][j]
// ---------------------------------------------------------------------------
__global__ __launch_bounds__(256)
void k_rowsum(const float* __restrict__ pm, float* __restrict__ msr) {
    int i = (blockIdx.x << 2) + (threadIdx.x >> 6);
    int lane = threadIdx.x & 63;
    const float4* row = (const float4*)&pm[(size_t)i << 10];
    float s = 0.f;
#pragma unroll
    for (int q = 0; q < 4; q++) {
        float4 v = row[(q << 6) + lane];
        s += v.x + v.y + v.z + v.w;
    }
#pragma unroll
    for (int off = 32; off; off >>= 1) s += __shfl_xor(s, off);
    if (lane == 0) msr[i] = s;
}

// ---------------------------------------------------------------------------
// Mask col sums: msc[j] = sum_i pair_mask[i][j]; grid 32, block 512
// ---------------------------------------------------------------------------
__global__ __launch_bounds__(512)
void k_colsum(const float* __restrict__ pm, float* __restrict__ msc) {
    __shared__ float red[512];
    int jb = blockIdx.x << 5;
    int jtl = threadIdx.x & 31, ig = threadIdx.x >> 5;  // 16 i-groups
    float s = 0.f;
    for (int i = ig; i < 1024; i += 16) s += pm[((size_t)i << 10) + jb + jtl];
    red[threadIdx.x] = s;
    __syncthreads();
    for (int st = 8; st > 0; st >>= 1) {
        if (ig < st) red[threadIdx.x] += red[threadIdx.x + (st << 5)];
        __syncthreads();
    }
    if (ig == 0) msc[jb + jtl] = red[jtl];
}

// ---------------------------------------------------------------------------
// Finalize u and vmix: u sums 16 slices, v sums 32 slices; divide by
// (mask sum + EPS). grid 1024 x 256: blocks [0,512) -> u, [512,1024) -> vmix
// ---------------------------------------------------------------------------
__global__ __launch_bounds__(256)
void k_fin(const float* __restrict__ up, const float* __restrict__ vp,
           const float* __restrict__ msr, const float* __restrict__ msc,
           float* __restrict__ uf, float* __restrict__ vf) {
    int b = blockIdx.x;
    if (b < 512) {
        int idx = (b << 8) + threadIdx.x;
        float s = 0.f;
#pragma unroll
        for (int t = 0; t < 16; t++) s += up[((size_t)t << 17) + idx];
        uf[idx] = s / (msr[idx >> 7] + EPSF);
    } else {
        int idx = ((b - 512) << 8) + threadIdx.x;
        float s = 0.f;
#pragma unroll
        for (int t = 0; t < 32; t++) s += vp[((size_t)t << 17) + idx];
        vf[idx] = s / (msc[idx >> 7] + EPSF);
    }
}

// ---------------------------------------------------------------------------
// K3: x = LN(atom_act); qa = x*(1+u); ka = x*(1+vmix). One wave per row.
// ---------------------------------------------------------------------------
__global__ __launch_bounds__(256)
void k3_act(const float* __restrict__ aa, const float* __restrict__ qns,
            const float* __restrict__ qnb, const float* __restrict__ uf,
            const float* __restrict__ vf, float* __restrict__ qa,
            float* __restrict__ ka) {
    int i = (blockIdx.x << 2) + (threadIdx.x >> 6);
    int lane = threadIdx.x & 63, c0 = lane << 1;
    float2 x2 = *(const float2*)&aa[(i << 7) + c0];
    float s = x2.x + x2.y, ss = x2.x * x2.x + x2.y * x2.y;
#pragma unroll
    for (int off = 32; off; off >>= 1) {
        s += __shfl_xor(s, off);
        ss += __shfl_xor(ss, off);
    }
    float m = s * 0.0078125f;
    float rinv = rsqrtf(fmaxf(ss * 0.0078125f - m * m, 0.f) + EPSF);
    float xa = (x2.x - m) * rinv * qns[c0] + qnb[c0];
    float xb = (x2.y - m) * rinv * qns[c0 + 1] + qnb[c0 + 1];
    float2 u2 = *(const float2*)&uf[(i << 7) + c0];
    float2 v2 = *(const float2*)&vf[(i << 7) + c0];
    *(float2*)&qa[(i << 7) + c0] = make_float2(xa * (1.f + u2.x), xb * (1.f + u2.y));
    *(float2*)&ka[(i << 7) + c0] = make_float2(xa * (1.f + v2.x), xb * (1.f + v2.y));
}

// ---------------------------------------------------------------------------
// K4: q/k/v/gate projections. grid (64 rowblocks, 4 mats), block 256.
// ---------------------------------------------------------------------------
__global__ __launch_bounds__(256)
void k4_proj(const float* __restrict__ qa, const float* __restrict__ ka,
             const float* __restrict__ wq, const float* __restrict__ wk,
             const float* __restrict__ wv, const float* __restrict__ wg,
             const float* __restrict__ bg, float* __restrict__ qh,
             float* __restrict__ kh, float* __restrict__ vT,
             float* __restrict__ gate) {
    __shared__ float Wl[128 * 128];
    __shared__ float inl[16 * 128];
    int m = blockIdx.y, rb = blockIdx.x, t = threadIdx.x;
    const float* W = (m == 0) ? wq : (m == 1) ? wk : (m == 2) ? wv : wg;
    const float* in = (m == 0 || m == 3) ? qa : ka;
#pragma unroll
    for (int k = 0; k < 16; k++)
        ((float4*)Wl)[(k << 8) + t] = ((const float4*)W)[(k << 8) + t];
#pragma unroll
    for (int k = 0; k < 2; k++)
        ((float4*)inl)[(k << 8) + t] = ((const float4*)&in[rb << 11])[(k << 8) + t];
    __syncthreads();

    int c = t & 127, r2 = t >> 7;
    float acc[8] = {0.f, 0.f, 0.f, 0.f, 0.f, 0.f, 0.f, 0.f};
    const float* wcol = &Wl[c];
    const float* ib = &inl[(r2 << 3) * 128];
#pragma unroll 8
    for (int k = 0; k < 128; k++) {
        float wvv = wcol[k << 7];
#pragma unroll
        for (int r = 0; r < 8; r++) acc[r] += ib[(r << 7) + k] * wvv;
    }
    int h = c >> 4, kk = c & 15;
    int row0 = (rb << 4) + (r2 << 3);
    if (m == 0) {
#pragma unroll
        for (int r = 0; r < 8; r++) qh[(h << 14) + ((row0 + r) << 4) + kk] = acc[r] * 0.25f;
    } else if (m == 1) {
#pragma unroll
        for (int r = 0; r < 8; r++) kh[(h << 14) + ((row0 + r) << 4) + kk] = acc[r];
    } else if (m == 2) {
#pragma unroll
        for (int r = 0; r < 8; r++) vT[(h << 14) + (kk << 10) + row0 + r] = acc[r];
    } else {
        float b = bg[c];
#pragma unroll
        for (int r = 0; r < 8; r++)
            gate[((row0 + r) << 7) + c] = 1.f / (1.f + __expf(-(acc[r] + b)));
    }
}

// ---------------------------------------------------------------------------
// K5: attention. One wave per (h,i). logits in regs, softmax via shfl.
// ---------------------------------------------------------------------------
__global__ __launch_bounds__(64)
void k5_attn(const float* __restrict__ qh, const float* __restrict__ kh,
             const float* __restrict__ vT, const float* __restrict__ pbias,
             const float* __restrict__ gate, float* __restrict__ wag) {
    __shared__ float p_lds[1024];
    int b = blockIdx.x;
    int h = b >> 10, i = b & 1023;
    int lane = threadIdx.x;

    const float* qp = &qh[(h << 14) + (i << 4)];
    float ql[16];
#pragma unroll
    for (int kk = 0; kk < 16; kk++) ql[kk] = qp[kk];

    const float* kbase = &kh[h << 14];
    const float* bias = &pbias[(((size_t)i << 3) + h) << 10];

    float lg[16];
    float mx = -1e30f;
#pragma unroll
    for (int jc = 0; jc < 16; jc++) {
        int j = (jc << 6) + lane;
        const float4* kr = (const float4*)&kbase[j << 4];
        float4 ka = kr[0], kb = kr[1], kc = kr[2], kd = kr[3];
        float acc = bias[j];
        acc += ql[0] * ka.x + ql[1] * ka.y + ql[2] * ka.z + ql[3] * ka.w;
        acc += ql[4] * kb.x + ql[5] * kb.y + ql[6] * kb.z + ql[7] * kb.w;
        acc += ql[8] * kc.x + ql[9] * kc.y + ql[10] * kc.z + ql[11] * kc.w;
        acc += ql[12] * kd.x + ql[13] * kd.y + ql[14] * kd.z + ql[15] * kd.w;
        lg[jc] = acc;
        mx = fmaxf(mx, acc);
    }
#pragma unroll
    for (int off = 32; off; off >>= 1) mx = fmaxf(mx, __shfl_xor(mx, off));
    float S = 0.f;
#pragma unroll
    for (int jc = 0; jc < 16; jc++) {
        float p = __expf(lg[jc] - mx);
        S += p;
        p_lds[(jc << 6) + lane] = p;
    }
#pragma unroll
    for (int off = 32; off; off >>= 1) S += __shfl_xor(S, off);
    float inv = 1.f / S;
    __syncthreads();

    int jj = lane >> 4, kk = lane & 15;
    const float* vp = &vT[(h << 14) + (kk << 10)];
    float acc = 0.f;
#pragma unroll 4
    for (int jb = 0; jb < 64; jb++) {
        int j4 = (jb << 4) + (jj << 2);
        float4 p4 = *(const float4*)&p_lds[j4];
        float4 v4 = *(const float4*)&vp[j4];
        acc += p4.x * v4.x + p4.y * v4.y + p4.z * v4.z + p4.w * v4.w;
    }
    acc += __shfl_xor(acc, 16);
    acc += __shfl_xor(acc, 32);
    if (lane < 16) {
        float g = gate[(i << 7) + (h << 4) + kk];
        wag[(i << 7) + (h << 4) + kk] = acc * inv * g;
    }
}

// ---------------------------------------------------------------------------
// K6: out = wag @ wo + bo
// ---------------------------------------------------------------------------
__global__ __launch_bounds__(256)
void k6_out(const float* __restrict__ wag, const float* __restrict__ wo,
            const float* __restrict__ bo, float* __restrict__ out) {
    __shared__ float Wl[128 * 128];
    __shared__ float inl[16 * 128];
    int rb = blockIdx.x, t = threadIdx.x;
#pragma unroll
    for (int k = 0; k < 16; k++)
        ((float4*)Wl)[(k << 8) + t] = ((const float4*)wo)[(k << 8) + t];
#pragma unroll
    for (int k = 0; k < 2; k++)
        ((float4*)inl)[(k << 8) + t] = ((const float4*)&wag[rb << 11])[(k << 8) + t];
    __syncthreads();

    int c = t & 127, r2 = t >> 7;
    float acc[8] = {0.f, 0.f, 0.f, 0.f, 0.f, 0.f, 0.f, 0.f};
    const float* wcol = &Wl[c];
    const float* ib = &inl[(r2 << 3) * 128];
#pragma unroll 8
    for (int k = 0; k < 128; k++) {
        float wvv = wcol[k << 7];
#pragma unroll
        for (int r = 0; r < 8; r++) acc[r] += ib[(r << 7) + k] * wvv;
    }
    int row0 = (rb << 4) + (r2 << 3);
    float b = bo[c];
#pragma unroll
    for (int r = 0; r < 8; r++) out[((row0 + r) << 7) + c] = acc[r] + b;
}

// ---------------------------------------------------------------------------
extern "C" void kernel_launch(void* const* d_in, const int* in_sizes, int n_in,
                              void* d_out, int out_size, void* d_ws, size_t ws_size,
                              hipStream_t stream) {
    const float* atom_act  = (const float*)d_in[0];
    const float* pair_act  = (const float*)d_in[1];
    // d_in[2] atom_mask: unused by reference output
    const float* pair_mask = (const float*)d_in[3];
    const float* qn_s = (const float*)d_in[4];
    const float* qn_b = (const float*)d_in[5];
    const float* f2n_s = (const float*)d_in[6];
    const float* f2n_b = (const float*)d_in[7];
    const float* mn_s = (const float*)d_in[8];
    const float* mn_b = (const float*)d_in[9];
    const float* w2d  = (const float*)d_in[10];
    const float* w_pm = (const float*)d_in[11];
    const float* b_pm = (const float*)d_in[12];
    const float* wq = (const float*)d_in[13];
    const float* wk = (const float*)d_in[14];
    const float* wv = (const float*)d_in[15];
    const float* wg = (const float*)d_in[16];
    const float* bg = (const float*)d_in[17];
    const float* wo = (const float*)d_in[18];
    const float* bo = (const float*)d_in[19];

    float* ws = (float*)d_ws;
    float* pbias  = ws;                          // 8M floats  (32 MB)
    float* u_part = pbias + 8 * 1024 * 1024;     // 16*1024*128 (8 MB)
    float* v_part = u_part + 16 * 1024 * 128;    // 32*1024*128 (16 MB)
    float* msr    = v_part + 32 * 1024 * 128;    // 1024
    float* msc    = msr + 1024;                  // 1024
    float* uf     = msc + 1024;                  // 131072
    float* vf     = uf + 131072;
    float* qa     = vf + 131072;
    float* ka     = qa + 131072;
    float* qh     = ka + 131072;
    float* kh     = qh + 131072;
    float* vT     = kh + 131072;
    float* gate   = vT + 131072;
    float* wag    = gate + 131072;
    (void)in_sizes; (void)n_in; (void)out_size; (void)ws_size;

    k_rowsum<<<256, 256, 0, stream>>>(pair_mask, msr);
    k_colsum<<<32, 512, 0, stream>>>(pair_mask, msc);
    k1_pair<<<512, 256, 0, stream>>>(pair_act, pair_mask, f2n_s, f2n_b, mn_s, mn_b,
                                     w2d, w_pm, b_pm, pbias, u_part, v_part);
    k_fin<<<1024, 256, 0, stream>>>(u_part, v_part, msr, msc, uf, vf);
    k3_act<<<256, 256, 0, stream>>>(atom_act, qn_s, qn_b, uf, vf, qa, ka);
    k4_proj<<<dim3(64, 4), 256, 0, stream>>>(qa, ka, wq, wk, wv, wg, bg, qh, kh, vT, gate);
    k5_attn<<<8192, 64, 0, stream>>>(qh, kh, vT, pbias, gate, wag);
    k6_out<<<64, 256, 0, stream>>>(wag, wo, bo, (float*)d_out);
}